// Round 1
// baseline (400.422 us; speedup 1.0000x reference)
//
#include <hip/hip_runtime.h>
#include <stdint.h>

#define D_DIM 1024
#define NA_DIM 4096
#define NV_DIM 4096

typedef __bf16 bf16_t;
typedef __bf16 bf16x8 __attribute__((ext_vector_type(8)));
typedef float f32x4 __attribute__((ext_vector_type(4)));

// async global->LDS, 16B per lane; LDS base must be wave-uniform (HW adds lane*16)
__device__ __forceinline__ void gload_lds16(const void* g, void* lds) {
  __builtin_amdgcn_global_load_lds(
      (const __attribute__((address_space(1))) unsigned int*)g,
      (__attribute__((address_space(3))) unsigned int*)lds, 16, 0, 0);
}

// ---------------- f32 -> bf16 convert (8 elems/thread) ----------------
__global__ __launch_bounds__(256) void cvt_f32_bf16(const float* __restrict__ in,
                                                    bf16_t* __restrict__ out, int n) {
  int i = (blockIdx.x * 256 + threadIdx.x) * 8;
  if (i >= n) return;
  float4 v0 = *(const float4*)(in + i);
  float4 v1 = *(const float4*)(in + i + 4);
  bf16x8 o;
  o[0] = (bf16_t)v0.x; o[1] = (bf16_t)v0.y; o[2] = (bf16_t)v0.z; o[3] = (bf16_t)v0.w;
  o[4] = (bf16_t)v1.x; o[5] = (bf16_t)v1.y; o[6] = (bf16_t)v1.z; o[7] = (bf16_t)v1.w;
  *(bf16x8*)(out + i) = o;
}

// ---------------- GEMM: C[m][n] = sum_k A[m][k]*B[n][k] (+residual) ----------------
// A: [M][K] bf16 row-major, B: [N][K] bf16 row-major (i.e. computes A @ B_rowmajor^T).
// 128x128 tile, 4 waves, each wave 64x64 via 4x4 mfma_f32_16x16x32_bf16 fragments.
// OUT_BF16: 1 -> bf16 C, 0 -> f32 C.  RESIDUAL: C += R[m][n] (f32).
template <int OUT_BF16, int RESIDUAL>
__global__ __launch_bounds__(256) void gemm_abt(const bf16_t* __restrict__ A,
                                                const bf16_t* __restrict__ B,
                                                void* __restrict__ Cv,
                                                const float* __restrict__ R,
                                                int M, int N, int K) {
  __shared__ bf16_t As[128 * 32];
  __shared__ bf16_t Bs[128 * 32];
  const int tid = threadIdx.x;
  const int lane = tid & 63;
  const int wid = tid >> 6;
  const int bm = blockIdx.x * 128;
  const int bn = blockIdx.y * 128;
  const int wr = (wid >> 1) * 64;   // wave row offset in tile
  const int wc = (wid & 1) * 64;    // wave col offset in tile
  const int frow = lane & 15;       // row/col within 16x16 fragment
  const int fko = (lane >> 4) * 8;  // k offset within 32 (consistent sigma for A and B)

  f32x4 acc[4][4] = {};

  // staging: 128x32 bf16 tile = 8KB; 256 thr * 16B = 4KB per issue -> 2 issues per tile
  const int e0 = tid * 8;          // elements 0..2047 (round 0); +2048 (round 1)
  const int r0 = e0 >> 5;          // 0..63
  const int c0 = e0 & 31;          // {0,8,16,24}
  const bf16_t* Ag = A + (size_t)(bm + r0) * K + c0;
  const bf16_t* Bg = B + (size_t)(bn + r0) * K + c0;
  const size_t rowskip = (size_t)64 * K;  // rows 64..127 (round 1)

  bf16_t* AsW0 = &As[wid * 512];
  bf16_t* AsW1 = &As[2048 + wid * 512];
  bf16_t* BsW0 = &Bs[wid * 512];
  bf16_t* BsW1 = &Bs[2048 + wid * 512];

  for (int k0 = 0; k0 < K; k0 += 32) {
    gload_lds16(Ag + k0, AsW0);
    gload_lds16(Ag + rowskip + k0, AsW1);
    gload_lds16(Bg + k0, BsW0);
    gload_lds16(Bg + rowskip + k0, BsW1);
    __syncthreads();  // drains vmcnt before barrier (compiler semantics)
    bf16x8 af[4], bfv[4];
#pragma unroll
    for (int i = 0; i < 4; ++i) {
      af[i] = *(const bf16x8*)&As[(wr + i * 16 + frow) * 32 + fko];
      bfv[i] = *(const bf16x8*)&Bs[(wc + i * 16 + frow) * 32 + fko];
    }
#pragma unroll
    for (int i = 0; i < 4; ++i)
#pragma unroll
      for (int j = 0; j < 4; ++j)
        acc[i][j] = __builtin_amdgcn_mfma_f32_16x16x32_bf16(af[i], bfv[j], acc[i][j], 0, 0, 0);
    __syncthreads();
  }

  // epilogue: verified C/D map: col = lane&15, row = (lane>>4)*4 + reg
  const int orow0 = wr + ((lane >> 4) << 2);
  const int ocol0 = wc + (lane & 15);
#pragma unroll
  for (int i = 0; i < 4; ++i)
#pragma unroll
    for (int j = 0; j < 4; ++j)
#pragma unroll
      for (int r = 0; r < 4; ++r) {
        size_t grow = (size_t)(bm + orow0 + i * 16 + r);
        size_t gcol = (size_t)(bn + ocol0 + j * 16);
        float v = acc[i][j][r];
        if constexpr (RESIDUAL) v += R[grow * N + gcol];
        if constexpr (OUT_BF16) {
          ((bf16_t*)Cv)[grow * N + gcol] = (bf16_t)v;
        } else {
          ((float*)Cv)[grow * N + gcol] = v;
        }
      }
}

// ---------------- row softmax: f32 [rows][4096] -> bf16 alpha ----------------
__global__ __launch_bounds__(256) void softmax_rows(const float* __restrict__ S,
                                                    bf16_t* __restrict__ P) {
  const int row = blockIdx.x;
  const int ncol = 4096;
  const float* s = S + (size_t)row * ncol;
  const int base = threadIdx.x * 16;
  float v[16];
  float4* vp = (float4*)v;
#pragma unroll
  for (int q = 0; q < 4; ++q) vp[q] = *(const float4*)(s + base + q * 4);
  float m = v[0];
#pragma unroll
  for (int q = 1; q < 16; ++q) m = fmaxf(m, v[q]);
  for (int off = 32; off; off >>= 1) m = fmaxf(m, __shfl_xor(m, off));
  __shared__ float sm[4], ss[4];
  const int wid = threadIdx.x >> 6, lane = threadIdx.x & 63;
  if (lane == 0) sm[wid] = m;
  __syncthreads();
  m = fmaxf(fmaxf(sm[0], sm[1]), fmaxf(sm[2], sm[3]));
  float sum = 0.f;
#pragma unroll
  for (int q = 0; q < 16; ++q) { v[q] = __expf(v[q] - m); sum += v[q]; }
  for (int off = 32; off; off >>= 1) sum += __shfl_xor(sum, off);
  if (lane == 0) ss[wid] = sum;
  __syncthreads();
  const float inv = 1.0f / (ss[0] + ss[1] + ss[2] + ss[3]);
  bf16x8 o0, o1;
#pragma unroll
  for (int q = 0; q < 8; ++q) { o0[q] = (bf16_t)(v[q] * inv); o1[q] = (bf16_t)(v[q + 8] * inv); }
  bf16_t* p = P + (size_t)row * ncol + base;
  *(bf16x8*)p = o0;
  *(bf16x8*)(p + 8) = o1;
}

// ---------------- bf16 transpose: in[R][C] -> out[C][R], 64x64 LDS tiles ----------------
__global__ __launch_bounds__(256) void transpose_bf16(const bf16_t* __restrict__ in,
                                                      bf16_t* __restrict__ out, int R, int C) {
  __shared__ bf16_t t[64][72];  // 72: keep 16B alignment (144B row) + conflict stagger
  const int bx = blockIdx.x * 64;  // col tile of in
  const int by = blockIdx.y * 64;  // row tile of in
  const int tid = threadIdx.x;
  const int c8 = (tid & 7) * 8;
  const int r = tid >> 3;  // 0..31
#pragma unroll
  for (int rr = 0; rr < 64; rr += 32) {
    bf16x8 v = *(const bf16x8*)(in + (size_t)(by + r + rr) * C + bx + c8);
    *(bf16x8*)&t[r + rr][c8] = v;
  }
  __syncthreads();
#pragma unroll
  for (int rr = 0; rr < 64; rr += 32) {
    bf16x8 v;
#pragma unroll
    for (int q = 0; q < 8; ++q) v[q] = t[c8 + q][r + rr];
    *(bf16x8*)(out + (size_t)(bx + r + rr) * R + by + c8) = v;
  }
}

extern "C" void kernel_launch(void* const* d_in, const int* in_sizes, int n_in,
                              void* d_out, int out_size, void* d_ws, size_t ws_size,
                              hipStream_t stream) {
  (void)in_sizes; (void)n_in; (void)out_size; (void)ws_size;
  const float* inA = (const float*)d_in[0];
  const float* inV = (const float*)d_in[1];
  const float* wBa = (const float*)d_in[2];
  const float* wAa = (const float*)d_in[3];
  const float* wBv = (const float*)d_in[4];
  const float* wAv = (const float*)d_in[5];
  float* out = (float*)d_out;

  // workspace layout (~210 MB total)
  char* w = (char*)d_ws;
  auto take = [&](size_t bytes) { void* p = (void*)w; w += bytes; return p; };
  const size_t XB = (size_t)NA_DIM * D_DIM * 2;   // 8 MB
  const size_t WB = (size_t)D_DIM * D_DIM * 2;    // 2 MB
  bf16_t* XaB = (bf16_t*)take(XB);
  bf16_t* XvB = (bf16_t*)take(XB);
  bf16_t* WBaB = (bf16_t*)take(WB);
  bf16_t* WAaB = (bf16_t*)take(WB);
  bf16_t* WBvB = (bf16_t*)take(WB);
  bf16_t* WAvB = (bf16_t*)take(WB);
  bf16_t* b_a = (bf16_t*)take(XB);
  bf16_t* a_v = (bf16_t*)take(XB);
  bf16_t* a_a = (bf16_t*)take(XB);
  bf16_t* b_v = (bf16_t*)take(XB);
  bf16_t* a_aT = (bf16_t*)take(XB);
  bf16_t* b_vT = (bf16_t*)take(XB);
  float* scores = (float*)take((size_t)NA_DIM * NV_DIM * 4);  // 64 MB
  bf16_t* alpha = (bf16_t*)take((size_t)NA_DIM * NV_DIM * 2);  // 32 MB
  bf16_t* alphaT = (bf16_t*)take((size_t)NA_DIM * NV_DIM * 2); // 32 MB

  const int nX = NA_DIM * D_DIM;   // 4M
  const int nW = D_DIM * D_DIM;    // 1M
  cvt_f32_bf16<<<nX / 2048, 256, 0, stream>>>(inA, XaB, nX);
  cvt_f32_bf16<<<nX / 2048, 256, 0, stream>>>(inV, XvB, nX);
  cvt_f32_bf16<<<nW / 2048, 256, 0, stream>>>(wBa, WBaB, nW);
  cvt_f32_bf16<<<nW / 2048, 256, 0, stream>>>(wAa, WAaB, nW);
  cvt_f32_bf16<<<nW / 2048, 256, 0, stream>>>(wBv, WBvB, nW);
  cvt_f32_bf16<<<nW / 2048, 256, 0, stream>>>(wAv, WAvB, nW);

  // stage 1: projections  y[i][o] = sum_k x[i][k] * W[o][k]
  dim3 g1(NA_DIM / 128, D_DIM / 128);
  gemm_abt<1, 0><<<g1, 256, 0, stream>>>(XaB, WBaB, b_a, nullptr, NA_DIM, D_DIM, D_DIM);
  gemm_abt<1, 0><<<g1, 256, 0, stream>>>(XvB, WAvB, a_v, nullptr, NV_DIM, D_DIM, D_DIM);
  gemm_abt<1, 0><<<g1, 256, 0, stream>>>(XaB, WAaB, a_a, nullptr, NA_DIM, D_DIM, D_DIM);
  gemm_abt<1, 0><<<g1, 256, 0, stream>>>(XvB, WBvB, b_v, nullptr, NV_DIM, D_DIM, D_DIM);

  // stage 2: scores[i][j] = sum_k b_a[i][k] * a_v[j][k]
  gemm_abt<0, 0><<<dim3(NA_DIM / 128, NV_DIM / 128), 256, 0, stream>>>(
      b_a, a_v, scores, nullptr, NA_DIM, NV_DIM, D_DIM);

  // stage 3: row softmax -> bf16 alpha
  softmax_rows<<<NA_DIM, 256, 0, stream>>>(scores, alpha);

  // transposes for k-major operands
  transpose_bf16<<<dim3(NV_DIM / 64, NA_DIM / 64), 256, 0, stream>>>(alpha, alphaT, NA_DIM, NV_DIM);
  transpose_bf16<<<dim3(D_DIM / 64, NA_DIM / 64), 256, 0, stream>>>(a_a, a_aT, NA_DIM, D_DIM);
  transpose_bf16<<<dim3(D_DIM / 64, NV_DIM / 64), 256, 0, stream>>>(b_v, b_vT, NV_DIM, D_DIM);

  // stage 4: out_a[i][d] = sum_j alpha[i][j] * b_vT[d][j] + inputs_a
  gemm_abt<0, 1><<<dim3(NA_DIM / 128, D_DIM / 128), 256, 0, stream>>>(
      alpha, b_vT, out, inA, NA_DIM, D_DIM, NV_DIM);
  // stage 5: out_v[j][d] = sum_i alphaT[j][i] * a_aT[d][i] + inputs_v
  gemm_abt<0, 1><<<dim3(NV_DIM / 128, D_DIM / 128), 256, 0, stream>>>(
      alphaT, a_aT, out + (size_t)NA_DIM * D_DIM, inV, NV_DIM, D_DIM, NA_DIM);
}

// Round 2
// 277.837 us; speedup vs baseline: 1.4412x; 1.4412x over previous
//
#include <hip/hip_runtime.h>
#include <stdint.h>

#define D_DIM 1024
#define NA_DIM 4096
#define NV_DIM 4096

typedef __bf16 bf16_t;
typedef __bf16 bf16x8 __attribute__((ext_vector_type(8)));
typedef float f32x4 __attribute__((ext_vector_type(4)));

// async global->LDS, 16B per lane; LDS base must be wave-uniform (HW adds lane*16)
__device__ __forceinline__ void gload_lds16(const void* g, void* lds) {
  __builtin_amdgcn_global_load_lds(
      (const __attribute__((address_space(1))) unsigned int*)g,
      (__attribute__((address_space(3))) unsigned int*)lds, 16, 0, 0);
}

// ---------------- GEMM core: acc += A[bm:+128][kb:ke] * B[bn:+128][kb:ke]^T ----------------
// LDS layout: linear [128][32] bf16 per matrix, but 16B chunks are permuted within each
// row pair: physical chunk pc at row r holds logical chunk pc ^ ((r>>1)&3).
// Staging (global_load_lds writes linearly) applies the inverse permutation on the
// global SOURCE column; fragment reads apply the same XOR on the LDS address.
// Result: each 16-lane quarter of a ds_read_b128 hits each bank group exactly twice
// (2-way = free, m136) instead of 8-way.
__device__ __forceinline__ void gemm_tile_core(const bf16_t* __restrict__ A,
                                               const bf16_t* __restrict__ B,
                                               int K, int kb, int ke, int bm, int bn,
                                               bf16_t* As, bf16_t* Bs, f32x4 acc[4][4]) {
  const int tid = threadIdx.x;
  const int lane = tid & 63;
  const int wid = tid >> 6;
  const int wr = (wid >> 1) * 64;   // wave row offset in tile
  const int wc = (wid & 1) * 64;    // wave col offset in tile
  const int frow = lane & 15;
  // swizzled k-chunk for fragment reads: chunk = hi ^ ((row>>1)&3); row = wr+i*16+frow,
  // and wr, i*16 contribute 0 mod 4 after >>1, so the XOR term is per-lane constant.
  const int fko = (((lane >> 4) ^ ((frow >> 1) & 3)) * 8);

  // staging: thread's physical LDS slot = linear element tid*8 -> (row=tid>>2, pchunk=tid&3)
  const int r0 = tid >> 2;
  const int c0 = (((tid & 3) ^ ((r0 >> 1) & 3)) * 8);  // inverse-swizzled source column
  const bf16_t* Ag = A + (size_t)(bm + r0) * K + kb + c0;
  const bf16_t* Bg = B + (size_t)(bn + r0) * K + kb + c0;
  const size_t rowskip = (size_t)64 * K;  // rows 64..127 (second issue; same XOR term)
  bf16_t* AsW0 = As + wid * 512;
  bf16_t* AsW1 = As + 2048 + wid * 512;
  bf16_t* BsW0 = Bs + wid * 512;
  bf16_t* BsW1 = Bs + 2048 + wid * 512;

  const int klen = ke - kb;
  for (int k0 = 0; k0 < klen; k0 += 32) {
    gload_lds16(Ag + k0, AsW0);
    gload_lds16(Ag + rowskip + k0, AsW1);
    gload_lds16(Bg + k0, BsW0);
    gload_lds16(Bg + rowskip + k0, BsW1);
    __syncthreads();  // compiler drains vmcnt before barrier
    bf16x8 af[4], bfv[4];
#pragma unroll
    for (int i = 0; i < 4; ++i) {
      af[i] = *(const bf16x8*)&As[(wr + i * 16 + frow) * 32 + fko];
      bfv[i] = *(const bf16x8*)&Bs[(wc + i * 16 + frow) * 32 + fko];
    }
#pragma unroll
    for (int i = 0; i < 4; ++i)
#pragma unroll
      for (int j = 0; j < 4; ++j)
        acc[i][j] = __builtin_amdgcn_mfma_f32_16x16x32_bf16(af[i], bfv[j], acc[i][j], 0, 0, 0);
    __syncthreads();
  }
}

// epilogue: verified C/D map: col = lane&15, row = (lane>>4)*4 + reg
template <int BF16OUT>
__device__ __forceinline__ void store_tile(void* Cv, int N, int bm, int bn, f32x4 acc[4][4]) {
  const int lane = threadIdx.x & 63;
  const int wid = threadIdx.x >> 6;
  const int wr = (wid >> 1) * 64;
  const int wc = (wid & 1) * 64;
  const int orow0 = wr + ((lane >> 4) << 2);
  const int ocol0 = wc + (lane & 15);
#pragma unroll
  for (int i = 0; i < 4; ++i)
#pragma unroll
    for (int j = 0; j < 4; ++j)
#pragma unroll
      for (int r = 0; r < 4; ++r) {
        size_t grow = (size_t)(bm + orow0 + i * 16 + r);
        size_t gcol = (size_t)(bn + ocol0 + j * 16);
        if constexpr (BF16OUT) {
          ((bf16_t*)Cv)[grow * N + gcol] = (bf16_t)acc[i][j][r];
        } else {
          ((float*)Cv)[grow * N + gcol] = acc[i][j][r];
        }
      }
}

// ---------------- batched projections: 4 GEMMs [4096,1024]x[1024,1024]^T, bf16 out ----------------
__global__ __launch_bounds__(256) void gemm_proj4(
    const bf16_t* __restrict__ Xa, const bf16_t* __restrict__ Xv,
    const bf16_t* __restrict__ W0, const bf16_t* __restrict__ W1,
    const bf16_t* __restrict__ W2, const bf16_t* __restrict__ W3,
    bf16_t* __restrict__ C0, bf16_t* __restrict__ C1,
    bf16_t* __restrict__ C2, bf16_t* __restrict__ C3) {
  __shared__ bf16_t As[4096], Bs[4096];
  const int z = blockIdx.z;
  const bf16_t* A = (z < 2) ? Xa : Xv;
  const bf16_t* B = (z == 0) ? W0 : (z == 1) ? W1 : (z == 2) ? W2 : W3;
  bf16_t* C = (z == 0) ? C0 : (z == 1) ? C1 : (z == 2) ? C2 : C3;
  f32x4 acc[4][4] = {};
  gemm_tile_core(A, B, D_DIM, 0, D_DIM, blockIdx.x * 128, blockIdx.y * 128, As, Bs, acc);
  store_tile<1>(C, D_DIM, blockIdx.x * 128, blockIdx.y * 128, acc);
}

// ---------------- scores GEMM: [4096,1024]x[4096,1024]^T -> f32 ----------------
__global__ __launch_bounds__(256) void gemm_scores(const bf16_t* __restrict__ A,
                                                   const bf16_t* __restrict__ B,
                                                   float* __restrict__ C) {
  __shared__ bf16_t As[4096], Bs[4096];
  f32x4 acc[4][4] = {};
  gemm_tile_core(A, B, D_DIM, 0, D_DIM, blockIdx.x * 128, blockIdx.y * 128, As, Bs, acc);
  store_tile<0>(C, NV_DIM, blockIdx.x * 128, blockIdx.y * 128, acc);
}

// ---------------- stage 4/5 batched split-K: z = gemm*2 + split ----------------
__global__ __launch_bounds__(256) void gemm_splitk(
    const bf16_t* __restrict__ alpha, const bf16_t* __restrict__ bvT,
    const bf16_t* __restrict__ alphaT, const bf16_t* __restrict__ aaT,
    float* __restrict__ P) {
  __shared__ bf16_t As[4096], Bs[4096];
  const int z = blockIdx.z;
  const bf16_t* A = (z < 2) ? alpha : alphaT;
  const bf16_t* B = (z < 2) ? bvT : aaT;
  const int kb = (z & 1) * 2048;
  f32x4 acc[4][4] = {};
  gemm_tile_core(A, B, 4096, kb, kb + 2048, blockIdx.x * 128, blockIdx.y * 128, As, Bs, acc);
  store_tile<0>(P + (size_t)z * NA_DIM * D_DIM, D_DIM, blockIdx.x * 128, blockIdx.y * 128, acc);
}

// ---------------- split-K reduce + residual add: out = P0 + P1 + res ----------------
__global__ __launch_bounds__(256) void reduce_splitk(const float* __restrict__ P,
                                                     const float* __restrict__ resA,
                                                     const float* __restrict__ resV,
                                                     float* __restrict__ out) {
  const int g = blockIdx.y;
  const size_t n = (size_t)NA_DIM * D_DIM;
  size_t i = ((size_t)blockIdx.x * 256 + threadIdx.x) * 4;
  const float* p0 = P + (size_t)g * 2 * n;
  const float* p1 = p0 + n;
  const float* r = g ? resV : resA;
  float4 a = *(const float4*)(p0 + i);
  float4 b = *(const float4*)(p1 + i);
  float4 c = *(const float4*)(r + i);
  float4 o = {a.x + b.x + c.x, a.y + b.y + c.y, a.z + b.z + c.z, a.w + b.w + c.w};
  *(float4*)(out + g * n + i) = o;
}

// ---------------- f32 -> bf16 converts (batched) ----------------
__device__ __forceinline__ void cvt8(const float* in, bf16_t* out, int i) {
  float4 v0 = *(const float4*)(in + i);
  float4 v1 = *(const float4*)(in + i + 4);
  bf16x8 o;
  o[0] = (bf16_t)v0.x; o[1] = (bf16_t)v0.y; o[2] = (bf16_t)v0.z; o[3] = (bf16_t)v0.w;
  o[4] = (bf16_t)v1.x; o[5] = (bf16_t)v1.y; o[6] = (bf16_t)v1.z; o[7] = (bf16_t)v1.w;
  *(bf16x8*)(out + i) = o;
}

__global__ __launch_bounds__(256) void cvt2(const float* __restrict__ inA,
                                            const float* __restrict__ inV,
                                            bf16_t* __restrict__ oA,
                                            bf16_t* __restrict__ oV) {
  const float* in = blockIdx.y ? inV : inA;
  bf16_t* out = blockIdx.y ? oV : oA;
  cvt8(in, out, (blockIdx.x * 256 + threadIdx.x) * 8);
}

__global__ __launch_bounds__(256) void cvt4(const float* __restrict__ i0, const float* __restrict__ i1,
                                            const float* __restrict__ i2, const float* __restrict__ i3,
                                            bf16_t* __restrict__ o0, bf16_t* __restrict__ o1,
                                            bf16_t* __restrict__ o2, bf16_t* __restrict__ o3) {
  const int z = blockIdx.y;
  const float* in = (z == 0) ? i0 : (z == 1) ? i1 : (z == 2) ? i2 : i3;
  bf16_t* out = (z == 0) ? o0 : (z == 1) ? o1 : (z == 2) ? o2 : o3;
  cvt8(in, out, (blockIdx.x * 256 + threadIdx.x) * 8);
}

// ---------------- row softmax: f32 [rows][4096] -> bf16 alpha ----------------
__global__ __launch_bounds__(256) void softmax_rows(const float* __restrict__ S,
                                                    bf16_t* __restrict__ P) {
  const int row = blockIdx.x;
  const int ncol = 4096;
  const float* s = S + (size_t)row * ncol;
  const int base = threadIdx.x * 16;
  float v[16];
  float4* vp = (float4*)v;
#pragma unroll
  for (int q = 0; q < 4; ++q) vp[q] = *(const float4*)(s + base + q * 4);
  float m = v[0];
#pragma unroll
  for (int q = 1; q < 16; ++q) m = fmaxf(m, v[q]);
  for (int off = 32; off; off >>= 1) m = fmaxf(m, __shfl_xor(m, off));
  __shared__ float sm[4], ss[4];
  const int wid = threadIdx.x >> 6, lane = threadIdx.x & 63;
  if (lane == 0) sm[wid] = m;
  __syncthreads();
  m = fmaxf(fmaxf(sm[0], sm[1]), fmaxf(sm[2], sm[3]));
  float sum = 0.f;
#pragma unroll
  for (int q = 0; q < 16; ++q) { v[q] = __expf(v[q] - m); sum += v[q]; }
  for (int off = 32; off; off >>= 1) sum += __shfl_xor(sum, off);
  if (lane == 0) ss[wid] = sum;
  __syncthreads();
  const float inv = 1.0f / (ss[0] + ss[1] + ss[2] + ss[3]);
  bf16x8 o0, o1;
#pragma unroll
  for (int q = 0; q < 8; ++q) { o0[q] = (bf16_t)(v[q] * inv); o1[q] = (bf16_t)(v[q + 8] * inv); }
  bf16_t* p = P + (size_t)row * ncol + base;
  *(bf16x8*)p = o0;
  *(bf16x8*)(p + 8) = o1;
}

// ---------------- bf16 transpose: in[R][C] -> out[C][R], 64x64 LDS tiles ----------------
__global__ __launch_bounds__(256) void transpose_bf16(const bf16_t* __restrict__ in,
                                                      bf16_t* __restrict__ out, int R, int C) {
  __shared__ bf16_t t[64][72];
  const int bx = blockIdx.x * 64;
  const int by = blockIdx.y * 64;
  const int tid = threadIdx.x;
  const int c8 = (tid & 7) * 8;
  const int r = tid >> 3;
#pragma unroll
  for (int rr = 0; rr < 64; rr += 32) {
    bf16x8 v = *(const bf16x8*)(in + (size_t)(by + r + rr) * C + bx + c8);
    *(bf16x8*)&t[r + rr][c8] = v;
  }
  __syncthreads();
#pragma unroll
  for (int rr = 0; rr < 64; rr += 32) {
    bf16x8 v;
#pragma unroll
    for (int q = 0; q < 8; ++q) v[q] = t[c8 + q][r + rr];
    *(bf16x8*)(out + (size_t)(bx + r + rr) * R + by + c8) = v;
  }
}

extern "C" void kernel_launch(void* const* d_in, const int* in_sizes, int n_in,
                              void* d_out, int out_size, void* d_ws, size_t ws_size,
                              hipStream_t stream) {
  (void)in_sizes; (void)n_in; (void)out_size; (void)ws_size;
  const float* inA = (const float*)d_in[0];
  const float* inV = (const float*)d_in[1];
  const float* wBa = (const float*)d_in[2];
  const float* wAa = (const float*)d_in[3];
  const float* wBv = (const float*)d_in[4];
  const float* wAv = (const float*)d_in[5];
  float* out = (float*)d_out;

  // workspace layout (~200 MB; split-K partials alias the dead scores buffer)
  char* w = (char*)d_ws;
  auto take = [&](size_t bytes) { void* p = (void*)w; w += bytes; return p; };
  const size_t XB = (size_t)NA_DIM * D_DIM * 2;   // 8 MB
  const size_t WB = (size_t)D_DIM * D_DIM * 2;    // 2 MB
  bf16_t* XaB = (bf16_t*)take(XB);
  bf16_t* XvB = (bf16_t*)take(XB);
  bf16_t* WBaB = (bf16_t*)take(WB);
  bf16_t* WAaB = (bf16_t*)take(WB);
  bf16_t* WBvB = (bf16_t*)take(WB);
  bf16_t* WAvB = (bf16_t*)take(WB);
  bf16_t* b_a = (bf16_t*)take(XB);
  bf16_t* a_v = (bf16_t*)take(XB);
  bf16_t* a_a = (bf16_t*)take(XB);
  bf16_t* b_v = (bf16_t*)take(XB);
  bf16_t* a_aT = (bf16_t*)take(XB);
  bf16_t* b_vT = (bf16_t*)take(XB);
  float* scores = (float*)take((size_t)NA_DIM * NV_DIM * 4);   // 64 MB (reused for partials)
  bf16_t* alpha = (bf16_t*)take((size_t)NA_DIM * NV_DIM * 2);  // 32 MB
  bf16_t* alphaT = (bf16_t*)take((size_t)NA_DIM * NV_DIM * 2); // 32 MB
  float* P = scores;  // split-K partials (4 x 16 MB), alias: scores dead after softmax

  // converts
  cvt2<<<dim3(NA_DIM * D_DIM / 2048, 2), 256, 0, stream>>>(inA, inV, XaB, XvB);
  cvt4<<<dim3(D_DIM * D_DIM / 2048, 4), 256, 0, stream>>>(wBa, wAa, wAv, wBv,
                                                          WBaB, WAaB, WAvB, WBvB);

  // stage 1: 4 projections, one batched launch (1024 blocks)
  gemm_proj4<<<dim3(NA_DIM / 128, D_DIM / 128, 4), 256, 0, stream>>>(
      XaB, XvB, WBaB, WAaB, WAvB, WBvB, b_a, a_a, a_v, b_v);

  // stage 2: scores[i][j] = sum_k b_a[i][k] * a_v[j][k]
  gemm_scores<<<dim3(NA_DIM / 128, NV_DIM / 128), 256, 0, stream>>>(b_a, a_v, scores);

  // stage 3: row softmax -> bf16 alpha
  softmax_rows<<<NA_DIM, 256, 0, stream>>>(scores, alpha);

  // transposes for k-major operands
  transpose_bf16<<<dim3(NV_DIM / 64, NA_DIM / 64), 256, 0, stream>>>(alpha, alphaT, NA_DIM, NV_DIM);
  transpose_bf16<<<dim3(D_DIM / 64, NA_DIM / 64), 256, 0, stream>>>(a_a, a_aT, NA_DIM, D_DIM);
  transpose_bf16<<<dim3(D_DIM / 64, NV_DIM / 64), 256, 0, stream>>>(b_v, b_vT, NV_DIM, D_DIM);

  // stages 4+5: batched split-K=2 (1024 blocks), then reduce+residual
  gemm_splitk<<<dim3(NA_DIM / 128, D_DIM / 128, 4), 256, 0, stream>>>(
      alpha, b_vT, alphaT, a_aT, P);
  reduce_splitk<<<dim3(NA_DIM * D_DIM / 1024, 2), 256, 0, stream>>>(P, inA, inV, out);
}

// Round 4
// 249.302 us; speedup vs baseline: 1.6062x; 1.1145x over previous
//
#include <hip/hip_runtime.h>
#include <stdint.h>

#define D_DIM 1024
#define NA_DIM 4096
#define NV_DIM 4096

typedef __bf16 bf16_t;
typedef __bf16 bf16x8 __attribute__((ext_vector_type(8)));
typedef float f32x4 __attribute__((ext_vector_type(4)));

// async global->LDS, 16B per lane; LDS base must be wave-uniform (HW adds lane*16)
__device__ __forceinline__ void gload_lds16(const void* g, void* lds) {
  __builtin_amdgcn_global_load_lds(
      (const __attribute__((address_space(1))) unsigned int*)g,
      (__attribute__((address_space(3))) unsigned int*)lds, 16, 0, 0);
}

// ================= 256x256 GEMM core, BK=32, double-buffered, counted vmcnt ==========
// C[m][n] = sum_k A[m][k]*B[n][k] over k in [kb, kb+klen); 512 threads = 8 waves (2Mx4N),
// per-wave output 128x64 (8x4 fragments of 16x16, mfma_f32_16x16x32_bf16).
// LDS: 2 buffers x (A 256x32 + B 256x32) bf16 = 64 KB. 16B-chunk swizzle within row-pairs
// (chunk ^= (row>>1)&3) applied on BOTH the global staging source and the ds_read address
// (rule #21: linear gload_lds dest + inverse-permuted source + same permutation on read)
// -> conflict-free ds_read_b128 (verified round 2: SQ_LDS_BANK_CONFLICT = 0).
// Pipeline: per tile t: issue tile t+1 staging -> s_waitcnt vmcnt(4) (tile t landed; the
// 4 fresh loads stay in flight across the barrier) -> barrier -> 2 phases x 16 MFMA with
// setprio -> barrier. Loads get a full tile (~1200 cyc) to land.
__device__ __forceinline__ void gemm256_core(const bf16_t* __restrict__ A,
                                             const bf16_t* __restrict__ B,
                                             int K, int kb, int klen, int bm, int bn,
                                             bf16_t* As, bf16_t* Bs, f32x4 acc[8][4]) {
  const int tid = threadIdx.x;
  const int lane = tid & 63;
  const int wid = tid >> 6;
  const int wm = wid >> 2;   // 0..1  wave row-half
  const int wn = wid & 3;    // 0..3  wave col-quarter
  const int frow = lane & 15;
  const int hi = lane >> 4;
  const int fko = ((hi ^ ((frow >> 1) & 3)) << 3);  // swizzled k-chunk for fragment reads

  // staging: thread's linear LDS slot = tid*8 elements -> (row = tid>>2, chunk = tid&3)
  const int r0 = tid >> 2;                               // 0..127
  const int c0 = (((tid & 3) ^ ((r0 >> 1) & 3)) << 3);   // inverse-swizzled source col
  const bf16_t* Ag = A + (size_t)(bm + r0) * K + kb + c0;
  const bf16_t* Bg = B + (size_t)(bn + r0) * K + kb + c0;
  const size_t rowskip = (size_t)128 * K;  // rows 128..255 (same swizzle term mod 4)
  bf16_t* AsW = As + wid * 512;
  bf16_t* BsW = Bs + wid * 512;

  const int NT = klen >> 5;
  // prologue: stage tile 0 into buffer 0
  gload_lds16(Ag, AsW);
  gload_lds16(Ag + rowskip, AsW + 4096);
  gload_lds16(Bg, BsW);
  gload_lds16(Bg + rowskip, BsW + 4096);

  for (int t = 0; t < NT; ++t) {
    const int cur = t & 1;
    if (t + 1 < NT) {
      const int nb = (cur ^ 1) * 8192;
      const bf16_t* Agn = Ag + (size_t)(t + 1) * 32;
      const bf16_t* Bgn = Bg + (size_t)(t + 1) * 32;
      gload_lds16(Agn, AsW + nb);
      gload_lds16(Agn + rowskip, AsW + nb + 4096);
      gload_lds16(Bgn, BsW + nb);
      gload_lds16(Bgn + rowskip, BsW + nb + 4096);
      asm volatile("s_waitcnt vmcnt(4)" ::: "memory");  // tile t landed; t+1 in flight
    } else {
      asm volatile("s_waitcnt vmcnt(0)" ::: "memory");  // tail: drain
    }
    __builtin_amdgcn_sched_barrier(0);
    __builtin_amdgcn_s_barrier();   // all waves' tile-t staging landed
    __builtin_amdgcn_sched_barrier(0);

    const bf16_t* Ab = As + cur * 8192;
    const bf16_t* Bb = Bs + cur * 8192;
    bf16x8 bfrag[4];
#pragma unroll
    for (int fc = 0; fc < 4; ++fc)
      bfrag[fc] = *(const bf16x8*)&Bb[(wn * 64 + fc * 16 + frow) * 32 + fko];
#pragma unroll
    for (int half = 0; half < 2; ++half) {
      bf16x8 afrag[4];
#pragma unroll
      for (int fr = 0; fr < 4; ++fr)
        afrag[fr] = *(const bf16x8*)&Ab[(wm * 128 + (half * 4 + fr) * 16 + frow) * 32 + fko];
      __builtin_amdgcn_s_setprio(1);
#pragma unroll
      for (int fr = 0; fr < 4; ++fr)
#pragma unroll
        for (int fc = 0; fc < 4; ++fc)
          acc[half * 4 + fr][fc] = __builtin_amdgcn_mfma_f32_16x16x32_bf16(
              afrag[fr], bfrag[fc], acc[half * 4 + fr][fc], 0, 0, 0);
      __builtin_amdgcn_s_setprio(0);
    }
    __builtin_amdgcn_sched_barrier(0);
    __builtin_amdgcn_s_barrier();   // all reads of buf[cur] done before t+2 staging lands there
    __builtin_amdgcn_sched_barrier(0);
  }
}

// epilogue: verified C/D map: col = lane&15, row = (lane>>4)*4 + reg
template <int BF16OUT>
__device__ __forceinline__ void store256(void* Cv, int ldc, int bm, int bn, f32x4 acc[8][4]) {
  const int lane = threadIdx.x & 63;
  const int wid = threadIdx.x >> 6;
  const int wm = wid >> 2, wn = wid & 3;
  const int frow = lane & 15, hi = lane >> 4;
  const int row0 = bm + wm * 128 + hi * 4;
  const int col0 = bn + wn * 64 + frow;
#pragma unroll
  for (int rf = 0; rf < 8; ++rf)
#pragma unroll
    for (int fc = 0; fc < 4; ++fc)
#pragma unroll
      for (int r = 0; r < 4; ++r) {
        size_t idx = (size_t)(row0 + rf * 16 + r) * ldc + (col0 + fc * 16);
        if constexpr (BF16OUT) ((bf16_t*)Cv)[idx] = (bf16_t)acc[rf][fc][r];
        else ((float*)Cv)[idx] = acc[rf][fc][r];
      }
}

// ---------------- batched projections: 4 GEMMs [4096,1024]x[1024,1024]^T, bf16 out ----
__global__ __launch_bounds__(512, 2) void gemm_proj4(
    const bf16_t* __restrict__ Xa, const bf16_t* __restrict__ Xv,
    const bf16_t* __restrict__ W0, const bf16_t* __restrict__ W1,
    const bf16_t* __restrict__ W2, const bf16_t* __restrict__ W3,
    bf16_t* __restrict__ C0, bf16_t* __restrict__ C1,
    bf16_t* __restrict__ C2, bf16_t* __restrict__ C3) {
  __shared__ bf16_t As[16384], Bs[16384];
  const int z = blockIdx.z;
  const bf16_t* A = (z < 2) ? Xa : Xv;
  const bf16_t* B = (z == 0) ? W0 : (z == 1) ? W1 : (z == 2) ? W2 : W3;
  bf16_t* C = (z == 0) ? C0 : (z == 1) ? C1 : (z == 2) ? C2 : C3;
  f32x4 acc[8][4] = {};
  gemm256_core(A, B, D_DIM, 0, D_DIM, blockIdx.x * 256, blockIdx.y * 256, As, Bs, acc);
  store256<1>(C, D_DIM, blockIdx.x * 256, blockIdx.y * 256, acc);
}

// ---------------- scores GEMM: [4096,1024]x[4096,1024]^T -> f32 ----------------
__global__ __launch_bounds__(512, 2) void gemm_scores(const bf16_t* __restrict__ A,
                                                      const bf16_t* __restrict__ B,
                                                      float* __restrict__ C) {
  __shared__ bf16_t As[16384], Bs[16384];
  f32x4 acc[8][4] = {};
  gemm256_core(A, B, D_DIM, 0, D_DIM, blockIdx.x * 256, blockIdx.y * 256, As, Bs, acc);
  store256<0>(C, NV_DIM, blockIdx.x * 256, blockIdx.y * 256, acc);
}

// ---------------- stage 4/5 batched split-K: z = gemm*2 + split ----------------
__global__ __launch_bounds__(512, 2) void gemm_splitk(
    const bf16_t* __restrict__ alpha, const bf16_t* __restrict__ bvT,
    const bf16_t* __restrict__ alphaT, const bf16_t* __restrict__ aaT,
    float* __restrict__ P) {
  __shared__ bf16_t As[16384], Bs[16384];
  const int z = blockIdx.z;
  const bf16_t* A = (z < 2) ? alpha : alphaT;
  const bf16_t* B = (z < 2) ? bvT : aaT;
  const int kb = (z & 1) * 2048;
  f32x4 acc[8][4] = {};
  gemm256_core(A, B, 4096, kb, 2048, blockIdx.x * 256, blockIdx.y * 256, As, Bs, acc);
  store256<0>(P + (size_t)z * NA_DIM * D_DIM, D_DIM, blockIdx.x * 256, blockIdx.y * 256, acc);
}

// ---------------- split-K reduce + residual add: out = P0 + P1 + res ----------------
__global__ __launch_bounds__(256) void reduce_splitk(const float* __restrict__ P,
                                                     const float* __restrict__ resA,
                                                     const float* __restrict__ resV,
                                                     float* __restrict__ out) {
  const int g = blockIdx.y;
  const size_t n = (size_t)NA_DIM * D_DIM;
  size_t i = ((size_t)blockIdx.x * 256 + threadIdx.x) * 4;
  const float* p0 = P + (size_t)g * 2 * n;
  const float* p1 = p0 + n;
  const float* r = g ? resV : resA;
  float4 a = *(const float4*)(p0 + i);
  float4 b = *(const float4*)(p1 + i);
  float4 c = *(const float4*)(r + i);
  float4 o = {a.x + b.x + c.x, a.y + b.y + c.y, a.z + b.z + c.z, a.w + b.w + c.w};
  *(float4*)(out + g * n + i) = o;
}

// ---------------- f32 -> bf16 converts (batched) ----------------
__device__ __forceinline__ void cvt8(const float* in, bf16_t* out, int i) {
  float4 v0 = *(const float4*)(in + i);
  float4 v1 = *(const float4*)(in + i + 4);
  bf16x8 o;
  o[0] = (bf16_t)v0.x; o[1] = (bf16_t)v0.y; o[2] = (bf16_t)v0.z; o[3] = (bf16_t)v0.w;
  o[4] = (bf16_t)v1.x; o[5] = (bf16_t)v1.y; o[6] = (bf16_t)v1.z; o[7] = (bf16_t)v1.w;
  *(bf16x8*)(out + i) = o;
}

__global__ __launch_bounds__(256) void cvt2(const float* __restrict__ inA,
                                            const float* __restrict__ inV,
                                            bf16_t* __restrict__ oA,
                                            bf16_t* __restrict__ oV) {
  const float* in = blockIdx.y ? inV : inA;
  bf16_t* out = blockIdx.y ? oV : oA;
  cvt8(in, out, (blockIdx.x * 256 + threadIdx.x) * 8);
}

__global__ __launch_bounds__(256) void cvt4(const float* __restrict__ i0, const float* __restrict__ i1,
                                            const float* __restrict__ i2, const float* __restrict__ i3,
                                            bf16_t* __restrict__ o0, bf16_t* __restrict__ o1,
                                            bf16_t* __restrict__ o2, bf16_t* __restrict__ o3) {
  const int z = blockIdx.y;
  const float* in = (z == 0) ? i0 : (z == 1) ? i1 : (z == 2) ? i2 : i3;
  bf16_t* out = (z == 0) ? o0 : (z == 1) ? o1 : (z == 2) ? o2 : o3;
  cvt8(in, out, (blockIdx.x * 256 + threadIdx.x) * 8);
}

// ---------------- row softmax: f32 [rows][4096] -> bf16 alpha ----------------
__global__ __launch_bounds__(256) void softmax_rows(const float* __restrict__ S,
                                                    bf16_t* __restrict__ P) {
  const int row = blockIdx.x;
  const int ncol = 4096;
  const float* s = S + (size_t)row * ncol;
  const int base = threadIdx.x * 16;
  float v[16];
  float4* vp = (float4*)v;
#pragma unroll
  for (int q = 0; q < 4; ++q) vp[q] = *(const float4*)(s + base + q * 4);
  float m = v[0];
#pragma unroll
  for (int q = 1; q < 16; ++q) m = fmaxf(m, v[q]);
  for (int off = 32; off; off >>= 1) m = fmaxf(m, __shfl_xor(m, off));
  __shared__ float sm[4], ss[4];
  const int wid = threadIdx.x >> 6, lane = threadIdx.x & 63;
  if (lane == 0) sm[wid] = m;
  __syncthreads();
  m = fmaxf(fmaxf(sm[0], sm[1]), fmaxf(sm[2], sm[3]));
  float sum = 0.f;
#pragma unroll
  for (int q = 0; q < 16; ++q) { v[q] = __expf(v[q] - m); sum += v[q]; }
  for (int off = 32; off; off >>= 1) sum += __shfl_xor(sum, off);
  if (lane == 0) ss[wid] = sum;
  __syncthreads();
  const float inv = 1.0f / (ss[0] + ss[1] + ss[2] + ss[3]);
  bf16x8 o0, o1;
#pragma unroll
  for (int q = 0; q < 8; ++q) { o0[q] = (bf16_t)(v[q] * inv); o1[q] = (bf16_t)(v[q + 8] * inv); }
  bf16_t* p = P + (size_t)row * ncol + base;
  *(bf16x8*)p = o0;
  *(bf16x8*)(p + 8) = o1;
}

// ---------------- bf16 transpose: in[R][C] -> out[C][R], 64x64 LDS tiles ----------------
__global__ __launch_bounds__(256) void transpose_bf16(const bf16_t* __restrict__ in,
                                                      bf16_t* __restrict__ out, int R, int C) {
  __shared__ bf16_t t[64][72];
  const int bx = blockIdx.x * 64;
  const int by = blockIdx.y * 64;
  const int tid = threadIdx.x;
  const int c8 = (tid & 7) * 8;
  const int r = tid >> 3;
#pragma unroll
  for (int rr = 0; rr < 64; rr += 32) {
    bf16x8 v = *(const bf16x8*)(in + (size_t)(by + r + rr) * C + bx + c8);
    *(bf16x8*)&t[r + rr][c8] = v;
  }
  __syncthreads();
#pragma unroll
  for (int rr = 0; rr < 64; rr += 32) {
    bf16x8 v;
#pragma unroll
    for (int q = 0; q < 8; ++q) v[q] = t[c8 + q][r + rr];
    *(bf16x8*)(out + (size_t)(bx + r + rr) * R + by + c8) = v;
  }
}

extern "C" void kernel_launch(void* const* d_in, const int* in_sizes, int n_in,
                              void* d_out, int out_size, void* d_ws, size_t ws_size,
                              hipStream_t stream) {
  (void)in_sizes; (void)n_in; (void)out_size; (void)ws_size;
  const float* inA = (const float*)d_in[0];
  const float* inV = (const float*)d_in[1];
  const float* wBa = (const float*)d_in[2];
  const float* wAa = (const float*)d_in[3];
  const float* wBv = (const float*)d_in[4];
  const float* wAv = (const float*)d_in[5];
  float* out = (float*)d_out;

  // workspace layout (~200 MB; split-K partials alias the dead scores buffer)
  char* w = (char*)d_ws;
  auto take = [&](size_t bytes) { void* p = (void*)w; w += bytes; return p; };
  const size_t XB = (size_t)NA_DIM * D_DIM * 2;   // 8 MB
  const size_t WB = (size_t)D_DIM * D_DIM * 2;    // 2 MB
  bf16_t* XaB = (bf16_t*)take(XB);
  bf16_t* XvB = (bf16_t*)take(XB);
  bf16_t* WBaB = (bf16_t*)take(WB);
  bf16_t* WAaB = (bf16_t*)take(WB);
  bf16_t* WBvB = (bf16_t*)take(WB);
  bf16_t* WAvB = (bf16_t*)take(WB);
  bf16_t* b_a = (bf16_t*)take(XB);
  bf16_t* a_v = (bf16_t*)take(XB);
  bf16_t* a_a = (bf16_t*)take(XB);
  bf16_t* b_v = (bf16_t*)take(XB);
  bf16_t* a_aT = (bf16_t*)take(XB);
  bf16_t* b_vT = (bf16_t*)take(XB);
  float* scores = (float*)take((size_t)NA_DIM * NV_DIM * 4);   // 64 MB (reused for partials)
  bf16_t* alpha = (bf16_t*)take((size_t)NA_DIM * NV_DIM * 2);  // 32 MB
  bf16_t* alphaT = (bf16_t*)take((size_t)NA_DIM * NV_DIM * 2); // 32 MB
  float* P = scores;  // split-K partials (4 x 16 MB), alias: scores dead after softmax

  // converts
  cvt2<<<dim3(NA_DIM * D_DIM / 2048, 2), 256, 0, stream>>>(inA, inV, XaB, XvB);
  cvt4<<<dim3(D_DIM * D_DIM / 2048, 4), 256, 0, stream>>>(wBa, wAa, wAv, wBv,
                                                          WBaB, WAaB, WAvB, WBvB);

  // stage 1: 4 projections, one batched launch (256 blocks = 1/CU)
  gemm_proj4<<<dim3(NA_DIM / 256, D_DIM / 256, 4), 512, 0, stream>>>(
      XaB, XvB, WBaB, WAaB, WAvB, WBvB, b_a, a_a, a_v, b_v);

  // stage 2: scores[i][j] = sum_k b_a[i][k] * a_v[j][k]  (256 blocks)
  gemm_scores<<<dim3(NA_DIM / 256, NV_DIM / 256), 512, 0, stream>>>(b_a, a_v, scores);

  // stage 3: row softmax -> bf16 alpha
  softmax_rows<<<NA_DIM, 256, 0, stream>>>(scores, alpha);

  // transposes for k-major operands
  transpose_bf16<<<dim3(NV_DIM / 64, NA_DIM / 64), 256, 0, stream>>>(alpha, alphaT, NA_DIM, NV_DIM);
  transpose_bf16<<<dim3(D_DIM / 64, NA_DIM / 64), 256, 0, stream>>>(a_a, a_aT, NA_DIM, D_DIM);
  transpose_bf16<<<dim3(D_DIM / 64, NV_DIM / 64), 256, 0, stream>>>(b_v, b_vT, NV_DIM, D_DIM);

  // stages 4+5: batched split-K=2 (256 blocks), then reduce+residual
  gemm_splitk<<<dim3(NA_DIM / 256, D_DIM / 256, 4), 512, 0, stream>>>(
      alpha, b_vT, alphaT, a_aT, P);
  reduce_splitk<<<dim3(NA_DIM * D_DIM / 1024, 2), 256, 0, stream>>>(P, inA, inV, out);
}

// Round 6
// 208.408 us; speedup vs baseline: 1.9213x; 1.1962x over previous
//
#include <hip/hip_runtime.h>
#include <stdint.h>

#define D_DIM 1024
#define NA_DIM 4096
#define NV_DIM 4096

typedef __bf16 bf16_t;
typedef __bf16 bf16x8 __attribute__((ext_vector_type(8)));
typedef float f32x4 __attribute__((ext_vector_type(4)));

// async global->LDS, 16B per lane; LDS base must be wave-uniform (HW adds lane*16)
__device__ __forceinline__ void gload_lds16(const void* g, void* lds) {
  __builtin_amdgcn_global_load_lds(
      (const __attribute__((address_space(1))) unsigned int*)g,
      (__attribute__((address_space(3))) unsigned int*)lds, 16, 0, 0);
}

// ================= 256x256 GEMM core, 8-phase schedule (T2+T3+T4+T5) ==================
// C[m][n] = sum_k A[m][k]*B[n][k], k in [kb, kb+klen). 512 threads = 8 waves (2M x 4N),
// per-wave output 128x64 = 8x4 fragments of mfma_f32_16x16x32_bf16.
// LDS: 128 KiB = 2 buffers x {A,B} x 2 half-tiles of 16 KB (128 rows x 64 k bf16).
// Swizzle (T2, rule #21 both-sides involution): 16B chunk pc = lc ^ (row&7); applied on
// the pre-swizzled global staging source AND the ds_read address; gload dest stays linear.
// -> each 16-lane quarter of ds_read_b128 hits each bank-group exactly twice (free).
// Schedule per iteration (2 K-tiles T=2i in buf0, T+1 in buf1), phases ph1..ph8;
// each phase: [vmcnt] barrier; issue 1 half-tile prefetch (2 gloads); ds_read quadrant
// (4 b128, +8 B-frags at q0); setprio(1); 16 MFMA; setprio(0); lgkmcnt(0).
//   ph1 (q0,buf0): vmcnt(4); issue (T+1).A0->buf1     ph5 (q0,buf1): vmcnt(4)*; (T+2).A0->buf0
//   ph2 (q1,buf0):           issue (T+1).A1->buf1     ph6 (q1,buf1):            (T+2).A1->buf0
//   ph3 (q2,buf0):           issue (T+2).B0->buf0     ph7 (q2,buf1):            (T+3).B0->buf1
//   ph4 (q3,buf0):           issue (T+2).B1->buf0     ph8 (q3,buf1):            (T+3).B1->buf1
// (* last iter: vmcnt(0); T+2/T+3 issues skipped.)
// Safety: every slot's prefetch is issued >=1 barrier after its last read executed
// (trailing lgkmcnt(0) forces reads to execute before the phase-end). vmcnt(4) at each
// q0 keeps exactly the 2 youngest half-tiles (4 gloads) in flight and forces the
// current K-tile's 4 half-tiles landed. Lookahead: A 3-4 phases, B 5-6 phases.
#define VMW(N) asm volatile("s_waitcnt vmcnt(" #N ")" ::: "memory")

__device__ __forceinline__ void gemm256_8ph(const bf16_t* __restrict__ A,
                                            const bf16_t* __restrict__ B,
                                            int K, int kb, int klen, int bm, int bn,
                                            bf16_t* lds, f32x4 acc[8][4]) {
  const int tid = threadIdx.x;
  const int lane = tid & 63;
  const int wid = tid >> 6;
  const int wm = wid >> 2;   // 0..1 : wave row-half (128 rows)
  const int wn = wid & 3;    // 0..3 : wave col-quarter (64 cols)
  const int frow = lane & 15;
  const int hi = lane >> 4;
  const int k0e = ((hi ^ (frow & 7)) << 3);   // swizzled k-chunk, ks=0 (elems); ks=1: ^32

  // staging source (pre-swizzled): lane -> row (lane>>3), logical chunk (lane&7)^(lane>>3)
  const int sr = (wid << 4) + (lane >> 3);              // 0..127 within half-tile
  const int sc = (((lane & 7) ^ (lane >> 3)) << 3);     // source col elems within 64
  const bf16_t* pAs = A + (size_t)(bm + sr) * K + kb + sc;
  const bf16_t* pBs = B + (size_t)(bn + sr) * K + kb + sc;
  const int dstW = wid << 10;                            // wave's 1024-elem LDS stripe

  // fragment read bases (elems): + buf*32768; A half = wm, B half = wn>>1, B row offset (wn&1)*64
  const int aBase = (wm << 13) + frow * 64 + k0e;
  const int bBase = 16384 + ((wn >> 1) << 13) + ((wn & 1) << 12) + frow * 64 + k0e;

#define STG_A(kt, h, bufb) do { \
    const bf16_t* s_ = pAs + (size_t)((h) * 128) * K + (size_t)(kt) * 64; \
    bf16_t* d_ = lds + (bufb) * 32768 + (h) * 8192 + dstW; \
    gload_lds16(s_, d_); gload_lds16(s_ + (size_t)8 * K, d_ + 512); } while (0)
#define STG_B(kt, h, bufb) do { \
    const bf16_t* s_ = pBs + (size_t)((h) * 128) * K + (size_t)(kt) * 64; \
    bf16_t* d_ = lds + (bufb) * 32768 + 16384 + (h) * 8192 + dstW; \
    gload_lds16(s_, d_); gload_lds16(s_ + (size_t)8 * K, d_ + 512); } while (0)

  bf16x8 bfr[4][2];  // B fragments, persist across the 4 phases of a K-tile

#define PHASE(BUFB, Q, ...) do { \
    asm volatile("s_barrier" ::: "memory"); \
    __VA_ARGS__; \
    const bf16_t* Lb = lds + (BUFB) * 32768; \
    if ((Q) == 0) { \
      _Pragma("unroll") for (int fc = 0; fc < 4; ++fc) { \
        bfr[fc][0] = *(const bf16x8*)&Lb[bBase + fc * 1024]; \
        bfr[fc][1] = *(const bf16x8*)&Lb[(bBase ^ 32) + fc * 1024]; \
      } \
    } \
    bf16x8 a00 = *(const bf16x8*)&Lb[aBase + (Q) * 2048]; \
    bf16x8 a01 = *(const bf16x8*)&Lb[(aBase ^ 32) + (Q) * 2048]; \
    bf16x8 a10 = *(const bf16x8*)&Lb[aBase + (Q) * 2048 + 1024]; \
    bf16x8 a11 = *(const bf16x8*)&Lb[(aBase ^ 32) + (Q) * 2048 + 1024]; \
    __builtin_amdgcn_s_setprio(1); \
    _Pragma("unroll") for (int fc = 0; fc < 4; ++fc) { \
      acc[(Q) * 2][fc]     = __builtin_amdgcn_mfma_f32_16x16x32_bf16(a00, bfr[fc][0], acc[(Q) * 2][fc], 0, 0, 0); \
      acc[(Q) * 2][fc]     = __builtin_amdgcn_mfma_f32_16x16x32_bf16(a01, bfr[fc][1], acc[(Q) * 2][fc], 0, 0, 0); \
      acc[(Q) * 2 + 1][fc] = __builtin_amdgcn_mfma_f32_16x16x32_bf16(a10, bfr[fc][0], acc[(Q) * 2 + 1][fc], 0, 0, 0); \
      acc[(Q) * 2 + 1][fc] = __builtin_amdgcn_mfma_f32_16x16x32_bf16(a11, bfr[fc][1], acc[(Q) * 2 + 1][fc], 0, 0, 0); \
    } \
    __builtin_amdgcn_s_setprio(0); \
    asm volatile("s_waitcnt lgkmcnt(0)" ::: "memory"); \
  } while (0)

  const int NI = klen >> 7;   // iterations of 2 K-tiles (klen/128)

  // prologue: tile0 {B,A} -> buf0, tile1 {B} -> buf1   (6 half-tiles = 12 gloads/wave)
  STG_B(0, 0, 0); STG_B(0, 1, 0); STG_A(0, 0, 0); STG_A(0, 1, 0);
  STG_B(1, 0, 1); STG_B(1, 1, 1);

  for (int it = 0; it < NI; ++it) {
    const int T = 2 * it;
    const bool more = (it + 1 < NI);
    VMW(4);
    PHASE(0, 0, { STG_A(T + 1, 0, 1); });
    PHASE(0, 1, { STG_A(T + 1, 1, 1); });
    PHASE(0, 2, { if (more) STG_B(T + 2, 0, 0); });
    PHASE(0, 3, { if (more) STG_B(T + 2, 1, 0); });
    if (more) { VMW(4); } else { VMW(0); }
    PHASE(1, 0, { if (more) STG_A(T + 2, 0, 0); });
    PHASE(1, 1, { if (more) STG_A(T + 2, 1, 0); });
    PHASE(1, 2, { if (more) STG_B(T + 3, 0, 1); });
    PHASE(1, 3, { if (more) STG_B(T + 3, 1, 1); });
  }
#undef PHASE
#undef STG_A
#undef STG_B
}

// epilogue: verified C/D map: col = lane&15, row = (lane>>4)*4 + reg
template <int BF16OUT>
__device__ __forceinline__ void store256(void* Cv, int ldc, int bm, int bn, f32x4 acc[8][4]) {
  const int lane = threadIdx.x & 63;
  const int wid = threadIdx.x >> 6;
  const int wm = wid >> 2, wn = wid & 3;
  const int frow = lane & 15, hi = lane >> 4;
  const int row0 = bm + wm * 128 + hi * 4;
  const int col0 = bn + wn * 64 + frow;
#pragma unroll
  for (int rf = 0; rf < 8; ++rf)
#pragma unroll
    for (int fc = 0; fc < 4; ++fc)
#pragma unroll
      for (int r = 0; r < 4; ++r) {
        size_t idx = (size_t)(row0 + rf * 16 + r) * ldc + (col0 + fc * 16);
        if constexpr (BF16OUT) ((bf16_t*)Cv)[idx] = (bf16_t)acc[rf][fc][r];
        else ((float*)Cv)[idx] = acc[rf][fc][r];
      }
}

// ---------------- batched projections: 4 GEMMs [4096,1024]x[1024,1024]^T, bf16 out ----
__global__ __launch_bounds__(512, 2) void gemm_proj4(
    const bf16_t* __restrict__ Xa, const bf16_t* __restrict__ Xv,
    const bf16_t* __restrict__ W0, const bf16_t* __restrict__ W1,
    const bf16_t* __restrict__ W2, const bf16_t* __restrict__ W3,
    bf16_t* __restrict__ C0, bf16_t* __restrict__ C1,
    bf16_t* __restrict__ C2, bf16_t* __restrict__ C3) {
  __shared__ bf16_t lds[65536];
  const int z = blockIdx.z;
  const bf16_t* A = (z < 2) ? Xa : Xv;
  const bf16_t* B = (z == 0) ? W0 : (z == 1) ? W1 : (z == 2) ? W2 : W3;
  bf16_t* C = (z == 0) ? C0 : (z == 1) ? C1 : (z == 2) ? C2 : C3;
  f32x4 acc[8][4] = {};
  gemm256_8ph(A, B, D_DIM, 0, D_DIM, blockIdx.x * 256, blockIdx.y * 256, lds, acc);
  store256<1>(C, D_DIM, blockIdx.x * 256, blockIdx.y * 256, acc);
}

// ---------------- scores GEMM: [4096,1024]x[4096,1024]^T -> f32 ----------------
__global__ __launch_bounds__(512, 2) void gemm_scores(const bf16_t* __restrict__ A,
                                                      const bf16_t* __restrict__ B,
                                                      float* __restrict__ C) {
  __shared__ bf16_t lds[65536];
  f32x4 acc[8][4] = {};
  gemm256_8ph(A, B, D_DIM, 0, D_DIM, blockIdx.x * 256, blockIdx.y * 256, lds, acc);
  store256<0>(C, NV_DIM, blockIdx.x * 256, blockIdx.y * 256, acc);
}

// ---------------- stage 4/5 batched split-K: z = gemm*2 + split ----------------
__global__ __launch_bounds__(512, 2) void gemm_splitk(
    const bf16_t* __restrict__ alpha, const bf16_t* __restrict__ bvT,
    const bf16_t* __restrict__ alphaT, const bf16_t* __restrict__ aaT,
    float* __restrict__ P) {
  __shared__ bf16_t lds[65536];
  const int z = blockIdx.z;
  const bf16_t* A = (z < 2) ? alpha : alphaT;
  const bf16_t* B = (z < 2) ? bvT : aaT;
  const int kb = (z & 1) * 2048;
  f32x4 acc[8][4] = {};
  gemm256_8ph(A, B, 4096, kb, 2048, blockIdx.x * 256, blockIdx.y * 256, lds, acc);
  store256<0>(P + (size_t)z * NA_DIM * D_DIM, D_DIM, blockIdx.x * 256, blockIdx.y * 256, acc);
}

// ---------------- split-K reduce + residual add: out = P0 + P1 + res ----------------
__global__ __launch_bounds__(256) void reduce_splitk(const float* __restrict__ P,
                                                     const float* __restrict__ resA,
                                                     const float* __restrict__ resV,
                                                     float* __restrict__ out) {
  const int g = blockIdx.y;
  const size_t n = (size_t)NA_DIM * D_DIM;
  size_t i = ((size_t)blockIdx.x * 256 + threadIdx.x) * 4;
  const float* p0 = P + (size_t)g * 2 * n;
  const float* p1 = p0 + n;
  const float* r = g ? resV : resA;
  float4 a = *(const float4*)(p0 + i);
  float4 b = *(const float4*)(p1 + i);
  float4 c = *(const float4*)(r + i);
  float4 o = {a.x + b.x + c.x, a.y + b.y + c.y, a.z + b.z + c.z, a.w + b.w + c.w};
  *(float4*)(out + g * n + i) = o;
}

// ---------------- f32 -> bf16 converts (batched) ----------------
__device__ __forceinline__ void cvt8(const float* in, bf16_t* out, int i) {
  float4 v0 = *(const float4*)(in + i);
  float4 v1 = *(const float4*)(in + i + 4);
  bf16x8 o;
  o[0] = (bf16_t)v0.x; o[1] = (bf16_t)v0.y; o[2] = (bf16_t)v0.z; o[3] = (bf16_t)v0.w;
  o[4] = (bf16_t)v1.x; o[5] = (bf16_t)v1.y; o[6] = (bf16_t)v1.z; o[7] = (bf16_t)v1.w;
  *(bf16x8*)(out + i) = o;
}

__global__ __launch_bounds__(256) void cvt2(const float* __restrict__ inA,
                                            const float* __restrict__ inV,
                                            bf16_t* __restrict__ oA,
                                            bf16_t* __restrict__ oV) {
  const float* in = blockIdx.y ? inV : inA;
  bf16_t* out = blockIdx.y ? oV : oA;
  cvt8(in, out, (blockIdx.x * 256 + threadIdx.x) * 8);
}

__global__ __launch_bounds__(256) void cvt4(const float* __restrict__ i0, const float* __restrict__ i1,
                                            const float* __restrict__ i2, const float* __restrict__ i3,
                                            bf16_t* __restrict__ o0, bf16_t* __restrict__ o1,
                                            bf16_t* __restrict__ o2, bf16_t* __restrict__ o3) {
  const int z = blockIdx.y;
  const float* in = (z == 0) ? i0 : (z == 1) ? i1 : (z == 2) ? i2 : i3;
  bf16_t* out = (z == 0) ? o0 : (z == 1) ? o1 : (z == 2) ? o2 : o3;
  cvt8(in, out, (blockIdx.x * 256 + threadIdx.x) * 8);
}

// ---------------- row softmax: f32 [rows][4096] -> bf16 alpha ----------------
__global__ __launch_bounds__(256) void softmax_rows(const float* __restrict__ S,
                                                    bf16_t* __restrict__ P) {
  const int row = blockIdx.x;
  const int ncol = 4096;
  const float* s = S + (size_t)row * ncol;
  const int base = threadIdx.x * 16;
  float v[16];
  float4* vp = (float4*)v;
#pragma unroll
  for (int q = 0; q < 4; ++q) vp[q] = *(const float4*)(s + base + q * 4);
  float m = v[0];
#pragma unroll
  for (int q = 1; q < 16; ++q) m = fmaxf(m, v[q]);
  for (int off = 32; off; off >>= 1) m = fmaxf(m, __shfl_xor(m, off));
  __shared__ float sm[4], ss[4];
  const int wid = threadIdx.x >> 6, lane = threadIdx.x & 63;
  if (lane == 0) sm[wid] = m;
  __syncthreads();
  m = fmaxf(fmaxf(sm[0], sm[1]), fmaxf(sm[2], sm[3]));
  float sum = 0.f;
#pragma unroll
  for (int q = 0; q < 16; ++q) { v[q] = __expf(v[q] - m); sum += v[q]; }
  for (int off = 32; off; off >>= 1) sum += __shfl_xor(sum, off);
  if (lane == 0) ss[wid] = sum;
  __syncthreads();
  const float inv = 1.0f / (ss[0] + ss[1] + ss[2] + ss[3]);
  bf16x8 o0, o1;
#pragma unroll
  for (int q = 0; q < 8; ++q) { o0[q] = (bf16_t)(v[q] * inv); o1[q] = (bf16_t)(v[q + 8] * inv); }
  bf16_t* p = P + (size_t)row * ncol + base;
  *(bf16x8*)p = o0;
  *(bf16x8*)(p + 8) = o1;
}

// ---------------- bf16 transpose: in[R][C] -> out[C][R], 64x64 LDS tiles ----------------
__global__ __launch_bounds__(256) void transpose_bf16(const bf16_t* __restrict__ in,
                                                      bf16_t* __restrict__ out, int R, int C) {
  __shared__ bf16_t t[64][72];
  const int bx = blockIdx.x * 64;
  const int by = blockIdx.y * 64;
  const int tid = threadIdx.x;
  const int c8 = (tid & 7) * 8;
  const int r = tid >> 3;
#pragma unroll
  for (int rr = 0; rr < 64; rr += 32) {
    bf16x8 v = *(const bf16x8*)(in + (size_t)(by + r + rr) * C + bx + c8);
    *(bf16x8*)&t[r + rr][c8] = v;
  }
  __syncthreads();
#pragma unroll
  for (int rr = 0; rr < 64; rr += 32) {
    bf16x8 v;
#pragma unroll
    for (int q = 0; q < 8; ++q) v[q] = t[c8 + q][r + rr];
    *(bf16x8*)(out + (size_t)(bx + r + rr) * R + by + c8) = v;
  }
}

extern "C" void kernel_launch(void* const* d_in, const int* in_sizes, int n_in,
                              void* d_out, int out_size, void* d_ws, size_t ws_size,
                              hipStream_t stream) {
  (void)in_sizes; (void)n_in; (void)out_size; (void)ws_size;
  const float* inA = (const float*)d_in[0];
  const float* inV = (const float*)d_in[1];
  const float* wBa = (const float*)d_in[2];
  const float* wAa = (const float*)d_in[3];
  const float* wBv = (const float*)d_in[4];
  const float* wAv = (const float*)d_in[5];
  float* out = (float*)d_out;

  // workspace layout (~200 MB; split-K partials alias the dead scores buffer)
  char* w = (char*)d_ws;
  auto take = [&](size_t bytes) { void* p = (void*)w; w += bytes; return p; };
  const size_t XB = (size_t)NA_DIM * D_DIM * 2;   // 8 MB
  const size_t WB = (size_t)D_DIM * D_DIM * 2;    // 2 MB
  bf16_t* XaB = (bf16_t*)take(XB);
  bf16_t* XvB = (bf16_t*)take(XB);
  bf16_t* WBaB = (bf16_t*)take(WB);
  bf16_t* WAaB = (bf16_t*)take(WB);
  bf16_t* WBvB = (bf16_t*)take(WB);
  bf16_t* WAvB = (bf16_t*)take(WB);
  bf16_t* b_a = (bf16_t*)take(XB);
  bf16_t* a_v = (bf16_t*)take(XB);
  bf16_t* a_a = (bf16_t*)take(XB);
  bf16_t* b_v = (bf16_t*)take(XB);
  bf16_t* a_aT = (bf16_t*)take(XB);
  bf16_t* b_vT = (bf16_t*)take(XB);
  float* scores = (float*)take((size_t)NA_DIM * NV_DIM * 4);   // 64 MB (reused for partials)
  bf16_t* alpha = (bf16_t*)take((size_t)NA_DIM * NV_DIM * 2);  // 32 MB
  bf16_t* alphaT = (bf16_t*)take((size_t)NA_DIM * NV_DIM * 2); // 32 MB
  float* P = scores;  // split-K partials (4 x 16 MB), alias: scores dead after softmax

  // converts
  cvt2<<<dim3(NA_DIM * D_DIM / 2048, 2), 256, 0, stream>>>(inA, inV, XaB, XvB);
  cvt4<<<dim3(D_DIM * D_DIM / 2048, 4), 256, 0, stream>>>(wBa, wAa, wAv, wBv,
                                                          WBaB, WAaB, WAvB, WBvB);

  // stage 1: 4 projections, one batched launch (256 blocks = 1/CU)
  gemm_proj4<<<dim3(NA_DIM / 256, D_DIM / 256, 4), 512, 0, stream>>>(
      XaB, XvB, WBaB, WAaB, WAvB, WBvB, b_a, a_a, a_v, b_v);

  // stage 2: scores[i][j] = sum_k b_a[i][k] * a_v[j][k]  (256 blocks)
  gemm_scores<<<dim3(NA_DIM / 256, NV_DIM / 256), 512, 0, stream>>>(b_a, a_v, scores);

  // stage 3: row softmax -> bf16 alpha
  softmax_rows<<<NA_DIM, 256, 0, stream>>>(scores, alpha);

  // transposes for k-major operands
  transpose_bf16<<<dim3(NV_DIM / 64, NA_DIM / 64), 256, 0, stream>>>(alpha, alphaT, NA_DIM, NV_DIM);
  transpose_bf16<<<dim3(D_DIM / 64, NA_DIM / 64), 256, 0, stream>>>(a_a, a_aT, NA_DIM, D_DIM);
  transpose_bf16<<<dim3(D_DIM / 64, NV_DIM / 64), 256, 0, stream>>>(b_v, b_vT, NV_DIM, D_DIM);

  // stages 4+5: batched split-K=2 (256 blocks), then reduce+residual
  gemm_splitk<<<dim3(NA_DIM / 256, D_DIM / 256, 4), 512, 0, stream>>>(
      alpha, b_vT, alphaT, a_aT, P);
  reduce_splitk<<<dim3(NA_DIM * D_DIM / 1024, 2), 256, 0, stream>>>(P, inA, inV, out);
}